// Round 10
// baseline (2003.085 us; speedup 1.0000x reference)
//
#include <hip/hip_runtime.h>
#include <hip/hip_cooperative_groups.h>
#include <math.h>

namespace cg = cooperative_groups;

#define HID 64
#define BN_EPS 1e-5f
#define NBMAX 256

typedef unsigned int uint;
typedef unsigned short ushort;

// ============ radix-bucketed CSR build (separate kernels, before mega) ============
// edges packed to 32-bit ((dst&255)<<16 | src) — requires N < 65536 (N=50000 here).

__global__ __launch_bounds__(256) void k_bucket_hist(const int* __restrict__ ei, int E, int NB,
                                                     int* __restrict__ bcnt_d, int* __restrict__ bcnt_s) {
    __shared__ int hd[NBMAX], hs[NBMAX];
    int t = threadIdx.x;
    if (t < NB) { hd[t] = 0; hs[t] = 0; }
    __syncthreads();
    for (int e = blockIdx.x * 256 + t; e < E; e += gridDim.x * 256) {
        int src = ei[e], dst = ei[E + e];
        atomicAdd(&hs[src >> 8], 1);
        atomicAdd(&hd[dst >> 8], 1);
    }
    __syncthreads();
    if (t < NB) {
        if (hd[t]) atomicAdd(&bcnt_d[t], hd[t]);
        if (hs[t]) atomicAdd(&bcnt_s[t], hs[t]);
    }
}

__global__ __launch_bounds__(256) void k_bucket_scan(const int* __restrict__ bcnt_d, const int* __restrict__ bcnt_s,
                                                     int NB, int N, int E,
                                                     int* __restrict__ bbase_d, int* __restrict__ cursor_d,
                                                     int* __restrict__ bbase_s, int* __restrict__ cursor_s,
                                                     int* __restrict__ rowptr) {
    __shared__ int sh[256];
    int t = threadIdx.x;
    int v = (t < NB) ? bcnt_d[t] : 0;
    sh[t] = v; __syncthreads();
    for (int s = 1; s < 256; s <<= 1) { int u = (t >= s) ? sh[t - s] : 0; __syncthreads(); sh[t] += u; __syncthreads(); }
    int excl = sh[t] - v;
    if (t <= NB) bbase_d[t] = excl;
    if (t < NB) cursor_d[t] = excl;
    if (t == 0) rowptr[N] = E;
    __syncthreads();
    v = (t < NB) ? bcnt_s[t] : 0;
    sh[t] = v; __syncthreads();
    for (int s = 1; s < 256; s <<= 1) { int u = (t >= s) ? sh[t - s] : 0; __syncthreads(); sh[t] += u; __syncthreads(); }
    excl = sh[t] - v;
    if (t <= NB) bbase_s[t] = excl;
    if (t < NB) cursor_s[t] = excl;
}

__global__ __launch_bounds__(256) void k_scatter(const int* __restrict__ ei, int E, int NB,
                                                 int* __restrict__ cursor_d, int* __restrict__ cursor_s,
                                                 uint* __restrict__ bedge, int* __restrict__ bsrc) {
    __shared__ int hd[NBMAX], hs[NBMAX], curd[NBMAX], curs[NBMAX];
    int t = threadIdx.x;
    int chunk = (E + gridDim.x - 1) / gridDim.x;
    int e0 = blockIdx.x * chunk;
    int e1 = min(e0 + chunk, E);
    if (t < NB) { hd[t] = 0; hs[t] = 0; }
    __syncthreads();
    for (int e = e0 + t; e < e1; e += 256) {
        int src = ei[e], dst = ei[E + e];
        atomicAdd(&hd[dst >> 8], 1);
        atomicAdd(&hs[src >> 8], 1);
    }
    __syncthreads();
    if (t < NB) {
        curd[t] = hd[t] ? atomicAdd(&cursor_d[t], hd[t]) : 0;
        curs[t] = hs[t] ? atomicAdd(&cursor_s[t], hs[t]) : 0;
    }
    __syncthreads();
    for (int e = e0 + t; e < e1; e += 256) {
        int src = ei[e], dst = ei[E + e];
        int pd = atomicAdd(&curd[dst >> 8], 1);
        bedge[pd] = ((uint)(dst & 255) << 16) | (uint)src;   // N < 65536
        int ps = atomicAdd(&curs[src >> 8], 1);
        bsrc[ps] = src;
    }
}

// fused: blocks [0,NB) build dst-CSR; blocks [NB,2NB) build outdeg->dis
__global__ __launch_bounds__(256) void k_build_csr_outdeg(const uint* __restrict__ bedge,
                                                          const int* __restrict__ bbase_d,
                                                          const int* __restrict__ bsrc,
                                                          const int* __restrict__ bbase_s,
                                                          int N, int NB,
                                                          int* __restrict__ rowptr, int* __restrict__ eidx,
                                                          float* __restrict__ dis) {
    __shared__ int h[256], off[256], cur[256];
    int t = threadIdx.x, b = blockIdx.x;
    if (b < NB) {
        int base = bbase_d[b], end = bbase_d[b + 1];
        h[t] = 0; __syncthreads();
        for (int p = base + t; p < end; p += 256)
            atomicAdd(&h[(int)(bedge[p] >> 16) & 255], 1);
        __syncthreads();
        off[t] = h[t]; __syncthreads();
        for (int s = 1; s < 256; s <<= 1) { int u = (t >= s) ? off[t - s] : 0; __syncthreads(); off[t] += u; __syncthreads(); }
        int excl = off[t] - h[t];
        int node = (b << 8) + t;
        if (node <= N) rowptr[node] = base + excl;
        cur[t] = excl; __syncthreads();
        for (int p = base + t; p < end; p += 256) {
            uint be = bedge[p];
            int bin = (int)(be >> 16) & 255;
            int pos = atomicAdd(&cur[bin], 1);
            eidx[base + pos] = (int)(be & 0xffffu);
        }
    } else {
        int b2 = b - NB;
        int base = bbase_s[b2], end = bbase_s[b2 + 1];
        h[t] = 0; __syncthreads();
        for (int p = base + t; p < end; p += 256) atomicAdd(&h[bsrc[p] & 255], 1);
        __syncthreads();
        int node = (b2 << 8) + t;
        if (node < N) dis[node] = rsqrtf((float)(h[t] + 1));
    }
}

// ============ helpers ============

__device__ inline uint bf16pk(float a, float b) {
    uint ua = __builtin_bit_cast(uint, a);
    ua += 0x7fff + ((ua >> 16) & 1);
    uint ub = __builtin_bit_cast(uint, b);
    ub += 0x7fff + ((ub >> 16) & 1);
    return (ua >> 16) | (ub & 0xffff0000u);
}
__device__ inline float bfl(uint v) { return __builtin_bit_cast(float, v << 16); }
__device__ inline float bfh(uint v) { return __builtin_bit_cast(float, v & 0xffff0000u); }

// ============ mega-kernel phases (device functions) ============

// P0: per-block col sums/sumsq of x [n,128] -> spartial[blk*256 + {0:128 sum,128:256 sq}]
__device__ inline void stats_x_phase(const float* __restrict__ X, int n,
                                     float* __restrict__ spartial, float* __restrict__ smem) {
    float4* shs = (float4*)smem;          // 256 float4
    float4* shq = shs + 256;              // 256 float4
    int t = threadIdx.x;
    int c4 = t & 31, rsub = t >> 5;
    float4 s = make_float4(0.f, 0.f, 0.f, 0.f);
    float4 q = make_float4(0.f, 0.f, 0.f, 0.f);
    for (int r = blockIdx.x * 8 + rsub; r < n; r += gridDim.x * 8) {
        float4 v = ((const float4*)X)[(size_t)r * 32 + c4];
        s.x += v.x; s.y += v.y; s.z += v.z; s.w += v.w;
        q.x = fmaf(v.x, v.x, q.x); q.y = fmaf(v.y, v.y, q.y);
        q.z = fmaf(v.z, v.z, q.z); q.w = fmaf(v.w, v.w, q.w);
    }
    shs[t] = s; shq[t] = q;
    __syncthreads();
    if (rsub == 0) {
        #pragma unroll
        for (int k = 1; k < 8; k++) {
            float4 a = shs[t + k * 32], b = shq[t + k * 32];
            s.x += a.x; s.y += a.y; s.z += a.z; s.w += a.w;
            q.x += b.x; q.y += b.y; q.z += b.z; q.w += b.w;
        }
        float* p = spartial + (size_t)blockIdx.x * 256;
        ((float4*)p)[c4] = s;
        ((float4*)(p + 128))[c4] = q;
    }
    __syncthreads();
}

// reduce spartial[:, j] over nblocks entries (stride = 2F); blocks [0, 2F)
__device__ inline void stats_final_phase(const float* __restrict__ partial, int stride2F, int nblocks,
                                         float* __restrict__ stats, float* __restrict__ smem) {
    int t = threadIdx.x;
    if (blockIdx.x < (uint)stride2F) {
        int j = blockIdx.x;
        float acc = 0.f;
        for (int b = t; b < nblocks; b += 256) acc += partial[(size_t)b * stride2F + j];
        smem[t] = acc;
        __syncthreads();
        #pragma unroll
        for (int off = 128; off > 0; off >>= 1) {
            if (t < off) smem[t] += smem[t + off];
            __syncthreads();
        }
        if (t == 0) stats[j] = smem[0];
        __syncthreads();
    }
}

// fold BN into W: blocks [0,64): block o handles output col o; stats[0:K)=sum,[K:2K)=sq
__device__ inline void fold_phase(int K, const float* __restrict__ stats, const float* __restrict__ gamma,
                                  const float* __restrict__ beta, const float* __restrict__ W,
                                  const float* __restrict__ bias, float n_inv,
                                  float* __restrict__ Wout, float* __restrict__ bout, bool has_bias,
                                  float* __restrict__ smem) {
    int o = blockIdx.x;
    int f = threadIdx.x;
    float contrib = 0.f;
    if (f < K) {
        float mu = stats[f] * n_inv;
        float var = stats[K + f] * n_inv - mu * mu;
        float a = gamma[f] * rsqrtf(var + BN_EPS);
        float w = W[(size_t)f * HID + o];
        Wout[(size_t)f * HID + o] = a * w;
        contrib = (beta[f] - mu * a) * w;
    }
    smem[f] = contrib;
    __syncthreads();
    #pragma unroll
    for (int off = 128; off > 0; off >>= 1) {
        if (f < off) smem[f] += smem[f + off];
        __syncthreads();
    }
    if (f == 0) bout[o] = smem[0] + (has_bias ? bias[o] : 0.f);
    __syncthreads();
}

// tiled GEMM phase, grid-stride over tiles of 64 rows
template <int K, bool RELU, bool DIS, bool STATS>
__device__ inline void gemm_phase(const float* __restrict__ X, const float* __restrict__ W,
                                  const float* __restrict__ bias, const float* __restrict__ dis,
                                  void* __restrict__ out, int n, int nTiles,
                                  float* __restrict__ smem, float* __restrict__ spartial) {
    constexpr int KC = 64;
    constexpr int XS = 68;
    float* Xs = smem;                // 64*68 = 4352 floats
    float* Wsm = smem + 4352;        // 4096 floats
    int t = threadIdx.x;
    int tx = t & 15, ty = t >> 4;
    float4 cs = make_float4(0.f, 0.f, 0.f, 0.f);
    float4 cq = make_float4(0.f, 0.f, 0.f, 0.f);

    for (int tile = blockIdx.x; tile < nTiles; tile += gridDim.x) {
        int row0 = tile * 64;
        float acc[4][4];
        #pragma unroll
        for (int i = 0; i < 4; i++)
            #pragma unroll
            for (int j = 0; j < 4; j++) acc[i][j] = 0.f;

        for (int kc = 0; kc < K; kc += KC) {
            #pragma unroll
            for (int it = 0; it < 4; ++it) {
                int id = t + 256 * it;
                int r = id >> 4, c4 = id & 15;
                float4 v = make_float4(0.f, 0.f, 0.f, 0.f);
                if (row0 + r < n) v = *(const float4*)(X + (size_t)(row0 + r) * K + kc + 4 * c4);
                int kk = 4 * c4;
                Xs[(kk + 0) * XS + r] = v.x;
                Xs[(kk + 1) * XS + r] = v.y;
                Xs[(kk + 2) * XS + r] = v.z;
                Xs[(kk + 3) * XS + r] = v.w;
            }
            {
                const float4* wsrc = (const float4*)(W + (size_t)kc * HID);
                #pragma unroll
                for (int it = 0; it < 4; ++it)
                    ((float4*)Wsm)[t + 256 * it] = wsrc[t + 256 * it];
            }
            __syncthreads();
            #pragma unroll 8
            for (int k = 0; k < KC; ++k) {
                float4 xv = *(const float4*)&Xs[k * XS + 4 * ty];
                float4 wv = *(const float4*)&Wsm[k * HID + 4 * tx];
                acc[0][0] = fmaf(xv.x, wv.x, acc[0][0]);
                acc[0][1] = fmaf(xv.x, wv.y, acc[0][1]);
                acc[0][2] = fmaf(xv.x, wv.z, acc[0][2]);
                acc[0][3] = fmaf(xv.x, wv.w, acc[0][3]);
                acc[1][0] = fmaf(xv.y, wv.x, acc[1][0]);
                acc[1][1] = fmaf(xv.y, wv.y, acc[1][1]);
                acc[1][2] = fmaf(xv.y, wv.z, acc[1][2]);
                acc[1][3] = fmaf(xv.y, wv.w, acc[1][3]);
                acc[2][0] = fmaf(xv.z, wv.x, acc[2][0]);
                acc[2][1] = fmaf(xv.z, wv.y, acc[2][1]);
                acc[2][2] = fmaf(xv.z, wv.z, acc[2][2]);
                acc[2][3] = fmaf(xv.z, wv.w, acc[2][3]);
                acc[3][0] = fmaf(xv.w, wv.x, acc[3][0]);
                acc[3][1] = fmaf(xv.w, wv.y, acc[3][1]);
                acc[3][2] = fmaf(xv.w, wv.z, acc[3][2]);
                acc[3][3] = fmaf(xv.w, wv.w, acc[3][3]);
            }
            __syncthreads();
        }

        float4 bv = *(const float4*)(bias + 4 * tx);
        #pragma unroll
        for (int i = 0; i < 4; ++i) {
            int row = row0 + 4 * ty + i;
            bool valid = row < n;
            float vx = acc[i][0] + bv.x, vy = acc[i][1] + bv.y;
            float vz = acc[i][2] + bv.z, vw = acc[i][3] + bv.w;
            if constexpr (DIS) {
                if (valid) {
                    float d = dis[row];
                    uint2 pk;
                    pk.x = bf16pk(vx * d, vy * d);
                    pk.y = bf16pk(vz * d, vw * d);
                    *(uint2*)((ushort*)out + (size_t)row * HID + 4 * tx) = pk;
                }
            } else {
                float4 v;
                v.x = RELU ? fmaxf(vx, 0.f) : vx;
                v.y = RELU ? fmaxf(vy, 0.f) : vy;
                v.z = RELU ? fmaxf(vz, 0.f) : vz;
                v.w = RELU ? fmaxf(vw, 0.f) : vw;
                if (valid) {
                    *(float4*)((float*)out + (size_t)row * HID + 4 * tx) = v;
                    if constexpr (STATS) {
                        cs.x += v.x; cs.y += v.y; cs.z += v.z; cs.w += v.w;
                        cq.x = fmaf(v.x, v.x, cq.x); cq.y = fmaf(v.y, v.y, cq.y);
                        cq.z = fmaf(v.z, v.z, cq.z); cq.w = fmaf(v.w, v.w, cq.w);
                    }
                }
            }
        }
        // no LDS access in epilogue -> safe to proceed to next tile's staging after the
        // k-loop's trailing __syncthreads()
    }
    if constexpr (STATS) {
        __syncthreads();
        float* reds = smem;
        float* redq = smem + 1024;
        *(float4*)&reds[ty * 64 + 4 * tx] = cs;
        *(float4*)&redq[ty * 64 + 4 * tx] = cq;
        __syncthreads();
        if (t < 64) {
            float s = 0.f, q = 0.f;
            #pragma unroll
            for (int k = 0; k < 16; ++k) { s += reds[k * 64 + t]; q += redq[k * 64 + t]; }
            spartial[(size_t)blockIdx.x * 128 + t] = s;
            spartial[(size_t)blockIdx.x * 128 + 64 + t] = q;
        }
        __syncthreads();
    }
}

// aggregation phase: grid-stride over groups of 8 nodes; always writes per-block stats partials
__device__ inline void agg_phase(const ushort* __restrict__ sbuf, const int* __restrict__ rowptr,
                                 const int* __restrict__ eidx, const float* __restrict__ dis,
                                 const float* __restrict__ bias, float* __restrict__ outh, int n,
                                 float* __restrict__ spartial, float* __restrict__ smem) {
    int t = threadIdx.x;
    int nl = t >> 5, li = t & 31, f = li * 2;
    int nGroups = (n + 7) >> 3;
    const uint* sp = (const uint*)sbuf;
    float2 bb = ((const float2*)bias)[li];
    float sx0 = 0.f, sx1 = 0.f, sq0 = 0.f, sq1 = 0.f;

    for (int g = blockIdx.x; g < nGroups; g += gridDim.x) {
        int i = g * 8 + nl;
        if (i < n) {
            uint v = sp[(size_t)i * 32 + li];
            float ax = bfl(v), ay = bfh(v);
            int q = rowptr[i], qe = rowptr[i + 1];
            for (; q + 8 <= qe; q += 8) {
                int j0 = eidx[q], j1 = eidx[q + 1], j2 = eidx[q + 2], j3 = eidx[q + 3];
                int j4 = eidx[q + 4], j5 = eidx[q + 5], j6 = eidx[q + 6], j7 = eidx[q + 7];
                uint v0 = sp[(size_t)j0 * 32 + li];
                uint v1 = sp[(size_t)j1 * 32 + li];
                uint v2 = sp[(size_t)j2 * 32 + li];
                uint v3 = sp[(size_t)j3 * 32 + li];
                uint v4 = sp[(size_t)j4 * 32 + li];
                uint v5 = sp[(size_t)j5 * 32 + li];
                uint v6 = sp[(size_t)j6 * 32 + li];
                uint v7 = sp[(size_t)j7 * 32 + li];
                ax += ((bfl(v0) + bfl(v1)) + (bfl(v2) + bfl(v3))) + ((bfl(v4) + bfl(v5)) + (bfl(v6) + bfl(v7)));
                ay += ((bfh(v0) + bfh(v1)) + (bfh(v2) + bfh(v3))) + ((bfh(v4) + bfh(v5)) + (bfh(v6) + bfh(v7)));
            }
            for (; q + 4 <= qe; q += 4) {
                int j0 = eidx[q], j1 = eidx[q + 1], j2 = eidx[q + 2], j3 = eidx[q + 3];
                uint v0 = sp[(size_t)j0 * 32 + li];
                uint v1 = sp[(size_t)j1 * 32 + li];
                uint v2 = sp[(size_t)j2 * 32 + li];
                uint v3 = sp[(size_t)j3 * 32 + li];
                ax += (bfl(v0) + bfl(v1)) + (bfl(v2) + bfl(v3));
                ay += (bfh(v0) + bfh(v1)) + (bfh(v2) + bfh(v3));
            }
            for (; q < qe; ++q) {
                uint vv = sp[(size_t)eidx[q] * 32 + li];
                ax += bfl(vv); ay += bfh(vv);
            }
            float dd = dis[i];
            float rx = fmaxf(fmaf(dd, ax, bb.x), 0.f);
            float ry = fmaxf(fmaf(dd, ay, bb.y), 0.f);
            *(float2*)(outh + (size_t)i * HID + f) = make_float2(rx, ry);
            sx0 += rx; sq0 = fmaf(rx, rx, sq0);
            sx1 += ry; sq1 = fmaf(ry, ry, sq1);
        }
    }
    smem[nl * 64 + f] = sx0;
    smem[nl * 64 + f + 1] = sx1;
    smem[512 + nl * 64 + f] = sq0;
    smem[512 + nl * 64 + f + 1] = sq1;
    __syncthreads();
    if (t < 64) {
        float ss = 0.f, qq = 0.f;
        #pragma unroll
        for (int k = 0; k < 8; ++k) { ss += smem[k * 64 + t]; qq += smem[512 + k * 64 + t]; }
        spartial[(size_t)blockIdx.x * 128 + t] = ss;
        spartial[(size_t)blockIdx.x * 128 + 64 + t] = qq;
    }
    __syncthreads();
}

// pool phase: grid-stride over graphs
__device__ inline void pool_phase(const float* __restrict__ h, const int* __restrict__ batch,
                                  int n, int G, float* __restrict__ outp, float* __restrict__ smem) {
    int t = threadIdx.x;
    int lane = t & 63, rs = t >> 6;
    for (int g = blockIdx.x; g < G; g += gridDim.x) {
        int lo = 0, hi = n;
        while (lo < hi) { int mid = (lo + hi) >> 1; if (batch[mid] < g) lo = mid + 1; else hi = mid; }
        int start = lo;
        hi = n;
        while (lo < hi) { int mid = (lo + hi) >> 1; if (batch[mid] < g + 1) lo = mid + 1; else hi = mid; }
        int end = lo;
        float acc = 0.f;
        for (int r = start + rs; r < end; r += 4) acc += h[(size_t)r * HID + lane];
        smem[t] = acc;
        __syncthreads();
        if (t < 64) outp[(size_t)g * HID + t] = smem[t] + smem[64 + t] + smem[128 + t] + smem[192 + t];
        __syncthreads();
    }
}

// ============ the cooperative mega-kernel ============

struct MegaArgs {
    const float* x;
    const float* bnfg; const float* bnfb;
    const float* Wfeat; const float* bfeat;
    const float* bng; const float* bnb;
    const float* WsAll; const float* bsAll;
    const int* rowptr; const int* eidx;
    const float* dis; const int* batch;
    float* out;
    float* stats; float* spartial;
    float* Wf; float* bf;
    float* bufA; ushort* bufB;
    int N; int G; int L;
};

__global__ __launch_bounds__(256, 4) void k_mega(MegaArgs a) {
    cg::grid_group grid = cg::this_grid();
    __shared__ __align__(16) float smem[8448];   // 33.8 KB: max over phases (gemm Xs+Ws)
    int nTiles = (a.N + 63) >> 6;

    // P0: stats over x
    stats_x_phase(a.x, a.N, a.spartial, smem);
    __threadfence(); grid.sync();
    // P1: finalize stats<128>
    stats_final_phase(a.spartial, 256, gridDim.x, a.stats, smem);
    __threadfence(); grid.sync();
    // P2: fold<128>
    if (blockIdx.x < 64)
        fold_phase(128, a.stats, a.bnfg, a.bnfb, a.Wfeat, a.bfeat, 1.f / (float)a.N, a.Wf, a.bf, true, smem);
    __threadfence(); grid.sync();
    // P3: gemm<128> x -> bufA (relu, f32) + fused stats partials
    gemm_phase<128, true, false, true>(a.x, a.Wf, a.bf, nullptr, (void*)a.bufA, a.N, nTiles, smem, a.spartial);
    __threadfence(); grid.sync();

    for (int l = 0; l < a.L; ++l) {
        // P4: finalize stats<64> (partials from gemm<128> or previous agg)
        stats_final_phase(a.spartial, 128, gridDim.x, a.stats, smem);
        __threadfence(); grid.sync();
        // P5: fold<64>
        if (blockIdx.x < 64)
            fold_phase(64, a.stats, a.bng + (size_t)l * HID, a.bnb + (size_t)l * HID,
                       a.WsAll + (size_t)l * HID * HID, nullptr, 1.f / (float)a.N, a.Wf, a.bf, false, smem);
        __threadfence(); grid.sync();
        // P6: gemm<64> bufA -> bufB (dis-scaled bf16)
        gemm_phase<64, false, true, false>(a.bufA, a.Wf, a.bf, a.dis, (void*)a.bufB, a.N, nTiles, smem, nullptr);
        __threadfence(); grid.sync();
        // P7: aggregation bufB -> bufA (+ stats partials for next layer)
        agg_phase(a.bufB, a.rowptr, a.eidx, a.dis, a.bsAll + (size_t)l * HID, a.bufA, a.N, a.spartial, smem);
        __threadfence(); grid.sync();
    }

    // P8: global_add_pool
    pool_phase(a.bufA, a.batch, a.N, a.G, a.out, smem);
}

// ============ driver ============

extern "C" void kernel_launch(void* const* d_in, const int* in_sizes, int n_in,
                              void* d_out, int out_size, void* d_ws, size_t ws_size,
                              hipStream_t stream) {
    const float* x     = (const float*)d_in[0];
    const int*   ei    = (const int*)d_in[1];
    const int*   batch = (const int*)d_in[2];
    const float* bnfg  = (const float*)d_in[3];
    const float* bnfb  = (const float*)d_in[4];
    const float* Wfeat = (const float*)d_in[5];
    const float* bfeat = (const float*)d_in[6];
    const float* bng   = (const float*)d_in[7];
    const float* bnb   = (const float*)d_in[8];
    const float* Ws    = (const float*)d_in[9];
    const float* bs    = (const float*)d_in[10];
    float* out = (float*)d_out;

    const int N   = in_sizes[2];
    const int E   = in_sizes[1] / 2;
    const int FIN = in_sizes[0] / N;
    const int L   = in_sizes[9] / (HID * HID);
    const int G   = out_size / HID;
    const int NB  = (N + 255) >> 8;

    char* w = (char*)d_ws;
    auto alloc = [&](size_t bytes) { char* p = w; w += (bytes + 255) & ~(size_t)255; return p; };
    int*   bcnt_d = (int*)alloc(256 * 4);
    int*   bcnt_s = (int*)alloc(256 * 4);
    size_t zero_bytes = (size_t)(w - (char*)d_ws);
    float* stats    = (float*)alloc(1024 * 4);
    float* spartial = (float*)alloc((size_t)1024 * 256 * 4);   // 1 MB (grid<=1024, stride<=256)
    int*   bbase_d  = (int*)alloc(257 * 4);
    int*   cursor_d = (int*)alloc(256 * 4);
    int*   bbase_s  = (int*)alloc(257 * 4);
    int*   cursor_s = (int*)alloc(256 * 4);
    int*   rowptr   = (int*)alloc(((size_t)N + 1) * 4);
    int*   eidx     = (int*)alloc((size_t)E * 4);
    float* dis      = (float*)alloc((size_t)N * 4);
    float* Wf       = (float*)alloc((size_t)FIN * HID * 4);
    float* bf       = (float*)alloc(HID * 4);
    float* bufA     = (float*)alloc((size_t)N * HID * 4);
    ushort* bufB    = (ushort*)alloc((size_t)N * HID * 2);
    uint* bedge = (uint*)bufA;     // E*4 <= N*HID*4 ; consumed before bufA first written
    int*  bsrc  = (int*)bufB;      // E*4 <= N*HID*2 ; consumed before bufB first written

    hipMemsetAsync(d_ws, 0, zero_bytes, stream);

    // graph build
    k_bucket_hist<<<256, 256, 0, stream>>>(ei, E, NB, bcnt_d, bcnt_s);
    k_bucket_scan<<<1, 256, 0, stream>>>(bcnt_d, bcnt_s, NB, N, E,
                                         bbase_d, cursor_d, bbase_s, cursor_s, rowptr);
    k_scatter<<<256, 256, 0, stream>>>(ei, E, NB, cursor_d, cursor_s, bedge, bsrc);
    k_build_csr_outdeg<<<2 * NB, 256, 0, stream>>>(bedge, bbase_d, bsrc, bbase_s, N, NB,
                                                   rowptr, eidx, dis);

    // cooperative mega-kernel: stats/fold/gemm/agg/pool all fused
    int occ = 0;
    hipOccupancyMaxActiveBlocksPerMultiprocessor(&occ, (const void*)k_mega, 256, 0);
    if (occ < 1) occ = 1;
    int gsz = occ * 256;            // 256 CUs on MI355X
    if (gsz > 1024) gsz = 1024;     // no benefit past 4 blocks/CU; sync cost grows
    if (gsz < 256) gsz = 256;       // stats_final<128> needs >=256 blocks

    MegaArgs margs;
    margs.x = x; margs.bnfg = bnfg; margs.bnfb = bnfb;
    margs.Wfeat = Wfeat; margs.bfeat = bfeat;
    margs.bng = bng; margs.bnb = bnb; margs.WsAll = Ws; margs.bsAll = bs;
    margs.rowptr = rowptr; margs.eidx = eidx; margs.dis = dis; margs.batch = batch;
    margs.out = out; margs.stats = stats; margs.spartial = spartial;
    margs.Wf = Wf; margs.bf = bf; margs.bufA = bufA; margs.bufB = bufB;
    margs.N = N; margs.G = G; margs.L = L;

    void* kargs[] = { (void*)&margs };
    hipLaunchCooperativeKernel((const void*)k_mega, dim3(gsz), dim3(256), kargs, 0, stream);
}

// Round 11
// 308.315 us; speedup vs baseline: 6.4969x; 6.4969x over previous
//
#include <hip/hip_runtime.h>
#include <math.h>

#define HID 64
#define BN_EPS 1e-5f
#define NBMAX 256

typedef unsigned int uint;
typedef unsigned short ushort;

// ============ radix-bucketed CSR build ============
// edges packed to 32-bit ((dst&255)<<16 | src) — requires N < 65536 (N=50000 here).

__global__ __launch_bounds__(256) void k_bucket_hist(const int* __restrict__ ei, int E, int NB,
                                                     int* __restrict__ bcnt_d, int* __restrict__ bcnt_s) {
    __shared__ int hd[NBMAX], hs[NBMAX];
    int t = threadIdx.x;
    if (t < NB) { hd[t] = 0; hs[t] = 0; }
    __syncthreads();
    for (int e = blockIdx.x * 256 + t; e < E; e += gridDim.x * 256) {
        int src = ei[e], dst = ei[E + e];
        atomicAdd(&hs[src >> 8], 1);
        atomicAdd(&hd[dst >> 8], 1);
    }
    __syncthreads();
    if (t < NB) {
        if (hd[t]) atomicAdd(&bcnt_d[t], hd[t]);
        if (hs[t]) atomicAdd(&bcnt_s[t], hs[t]);
    }
}

__global__ __launch_bounds__(256) void k_bucket_scan(const int* __restrict__ bcnt_d, const int* __restrict__ bcnt_s,
                                                     int NB, int N, int E,
                                                     int* __restrict__ bbase_d, int* __restrict__ cursor_d,
                                                     int* __restrict__ bbase_s, int* __restrict__ cursor_s,
                                                     int* __restrict__ rowptr) {
    __shared__ int sh[256];
    int t = threadIdx.x;
    int v = (t < NB) ? bcnt_d[t] : 0;
    sh[t] = v; __syncthreads();
    for (int s = 1; s < 256; s <<= 1) { int u = (t >= s) ? sh[t - s] : 0; __syncthreads(); sh[t] += u; __syncthreads(); }
    int excl = sh[t] - v;
    if (t <= NB) bbase_d[t] = excl;
    if (t < NB) cursor_d[t] = excl;
    if (t == 0) rowptr[N] = E;
    __syncthreads();
    v = (t < NB) ? bcnt_s[t] : 0;
    sh[t] = v; __syncthreads();
    for (int s = 1; s < 256; s <<= 1) { int u = (t >= s) ? sh[t - s] : 0; __syncthreads(); sh[t] += u; __syncthreads(); }
    excl = sh[t] - v;
    if (t <= NB) bbase_s[t] = excl;
    if (t < NB) cursor_s[t] = excl;
}

__global__ __launch_bounds__(256) void k_scatter(const int* __restrict__ ei, int E, int NB,
                                                 int* __restrict__ cursor_d, int* __restrict__ cursor_s,
                                                 uint* __restrict__ bedge, int* __restrict__ bsrc) {
    __shared__ int hd[NBMAX], hs[NBMAX], curd[NBMAX], curs[NBMAX];
    int t = threadIdx.x;
    int chunk = (E + gridDim.x - 1) / gridDim.x;
    int e0 = blockIdx.x * chunk;
    int e1 = min(e0 + chunk, E);
    if (t < NB) { hd[t] = 0; hs[t] = 0; }
    __syncthreads();
    for (int e = e0 + t; e < e1; e += 256) {
        int src = ei[e], dst = ei[E + e];
        atomicAdd(&hd[dst >> 8], 1);
        atomicAdd(&hs[src >> 8], 1);
    }
    __syncthreads();
    if (t < NB) {
        curd[t] = hd[t] ? atomicAdd(&cursor_d[t], hd[t]) : 0;
        curs[t] = hs[t] ? atomicAdd(&cursor_s[t], hs[t]) : 0;
    }
    __syncthreads();
    for (int e = e0 + t; e < e1; e += 256) {
        int src = ei[e], dst = ei[E + e];
        int pd = atomicAdd(&curd[dst >> 8], 1);
        bedge[pd] = ((uint)(dst & 255) << 16) | (uint)src;   // N < 65536
        int ps = atomicAdd(&curs[src >> 8], 1);
        bsrc[ps] = src;
    }
}

// fused: blocks [0,NB) build dst-CSR; blocks [NB,2NB) build outdeg->dis
__global__ __launch_bounds__(256) void k_build_csr_outdeg(const uint* __restrict__ bedge,
                                                          const int* __restrict__ bbase_d,
                                                          const int* __restrict__ bsrc,
                                                          const int* __restrict__ bbase_s,
                                                          int N, int NB,
                                                          int* __restrict__ rowptr, int* __restrict__ eidx,
                                                          float* __restrict__ dis) {
    __shared__ int h[256], off[256], cur[256];
    int t = threadIdx.x, b = blockIdx.x;
    if (b < NB) {
        int base = bbase_d[b], end = bbase_d[b + 1];
        h[t] = 0; __syncthreads();
        for (int p = base + t; p < end; p += 256)
            atomicAdd(&h[(int)(bedge[p] >> 16) & 255], 1);
        __syncthreads();
        off[t] = h[t]; __syncthreads();
        for (int s = 1; s < 256; s <<= 1) { int u = (t >= s) ? off[t - s] : 0; __syncthreads(); off[t] += u; __syncthreads(); }
        int excl = off[t] - h[t];
        int node = (b << 8) + t;
        if (node <= N) rowptr[node] = base + excl;
        cur[t] = excl; __syncthreads();
        for (int p = base + t; p < end; p += 256) {
            uint be = bedge[p];
            int bin = (int)(be >> 16) & 255;
            int pos = atomicAdd(&cur[bin], 1);
            eidx[base + pos] = (int)(be & 0xffffu);
        }
    } else {
        int b2 = b - NB;
        int base = bbase_s[b2], end = bbase_s[b2 + 1];
        h[t] = 0; __syncthreads();
        for (int p = base + t; p < end; p += 256) atomicAdd(&h[bsrc[p] & 255], 1);
        __syncthreads();
        int node = (b2 << 8) + t;
        if (node < N) dis[node] = rsqrtf((float)(h[t] + 1));
    }
}

// ============ BN stats over x (stage 1) ============

template <int F>
__global__ __launch_bounds__(256) void k_stats(const float* __restrict__ X, int n,
                                               float* __restrict__ partial) {
    constexpr int C4 = F / 4;
    constexpr int RPB = 256 / C4;
    int t = threadIdx.x;
    int c4 = t % C4;
    int rsub = t / C4;
    float4 s = make_float4(0.f, 0.f, 0.f, 0.f);
    float4 q = make_float4(0.f, 0.f, 0.f, 0.f);
    for (int r = blockIdx.x * RPB + rsub; r < n; r += gridDim.x * RPB) {
        float4 v = *(const float4*)(X + (size_t)r * F + 4 * c4);
        s.x += v.x; s.y += v.y; s.z += v.z; s.w += v.w;
        q.x = fmaf(v.x, v.x, q.x); q.y = fmaf(v.y, v.y, q.y);
        q.z = fmaf(v.z, v.z, q.z); q.w = fmaf(v.w, v.w, q.w);
    }
    __shared__ float4 shs[256], shq[256];
    shs[t] = s; shq[t] = q;
    __syncthreads();
    if (rsub == 0) {
        #pragma unroll
        for (int k = 1; k < RPB; k++) {
            float4 a = shs[t + k * C4], b = shq[t + k * C4];
            s.x += a.x; s.y += a.y; s.z += a.z; s.w += a.w;
            q.x += b.x; q.y += b.y; q.z += b.z; q.w += b.w;
        }
        float* p = partial + (size_t)blockIdx.x * (2 * F);
        *(float4*)(p + 4 * c4) = s;
        *(float4*)(p + F + 4 * c4) = q;
    }
}

// grid = 2F blocks, 256 threads: block j reduces partial[:, j] over nblocks entries.
template <int F>
__global__ __launch_bounds__(256) void k_stats_final(const float* __restrict__ partial, int nblocks,
                                                     float* __restrict__ stats) {
    int j = blockIdx.x;
    int t = threadIdx.x;
    float acc = 0.f;
    for (int b = t; b < nblocks; b += 256) acc += partial[(size_t)b * (2 * F) + j];
    __shared__ float sh[256];
    sh[t] = acc;
    __syncthreads();
    #pragma unroll
    for (int off = 128; off > 0; off >>= 1) {
        if (t < off) sh[t] += sh[t + off];
        __syncthreads();
    }
    if (t == 0) stats[j] = sh[0];
}

// ============ GEMM with fused BN-fold prologue + optional stats epilogue ============
// Per block (redundantly, cheap): a[f]=gamma*rsqrt(var+eps), c[f]=beta-mu*a from stats;
// W staged scaled (a[k]*W[k][col]); folded bias b[o]=sum_f c[f]*W_raw[f][o] (+bias0)
// accumulated during staging, LDS-reduced before the epilogue.

__device__ inline uint bf16pk(float a, float b) {
    uint ua = __builtin_bit_cast(uint, a);
    ua += 0x7fff + ((ua >> 16) & 1);
    uint ub = __builtin_bit_cast(uint, b);
    ub += 0x7fff + ((ub >> 16) & 1);
    return (ua >> 16) | (ub & 0xffff0000u);
}
__device__ inline float bfl(uint v) { return __builtin_bit_cast(float, v << 16); }
__device__ inline float bfh(uint v) { return __builtin_bit_cast(float, v & 0xffff0000u); }

template <int K, bool RELU, bool DIS, bool STATS, bool HASB>
__global__ __launch_bounds__(256) void k_gemm(const float* __restrict__ X, const float* __restrict__ W,
                                              const float* __restrict__ stats,
                                              const float* __restrict__ gamma, const float* __restrict__ beta,
                                              const float* __restrict__ bias0, const float* __restrict__ dis,
                                              float n_inv, void* __restrict__ out, int n,
                                              float* __restrict__ spartial) {
    constexpr int KC = 64;
    constexpr int XS = 68;
    __shared__ float Xs[KC * XS];     // staging + post-loop reduction scratch
    __shared__ float Wsm[KC * HID];   // scaled W chunk
    __shared__ float As[128], Cs[128];

    int t = threadIdx.x;
    int tx = t & 15, ty = t >> 4;
    int row0 = blockIdx.x * 64;

    // fold prologue
    if (t < K) {
        float mu = stats[t] * n_inv;
        float var = stats[K + t] * n_inv - mu * mu;
        float a = gamma[t] * rsqrtf(var + BN_EPS);
        As[t] = a;
        Cs[t] = beta[t] - mu * a;
    }
    __syncthreads();

    float acc[4][4];
    #pragma unroll
    for (int i = 0; i < 4; i++)
        #pragma unroll
        for (int j = 0; j < 4; j++) acc[i][j] = 0.f;
    float4 bp = make_float4(0.f, 0.f, 0.f, 0.f);   // folded-bias partial for cols 4tx..4tx+3

    for (int kc = 0; kc < K; kc += KC) {
        #pragma unroll
        for (int it = 0; it < 4; ++it) {
            int id = t + 256 * it;
            int r = id >> 4, c4 = id & 15;
            float4 v = make_float4(0.f, 0.f, 0.f, 0.f);
            if (row0 + r < n) v = *(const float4*)(X + (size_t)(row0 + r) * K + kc + 4 * c4);
            int kk = 4 * c4;
            Xs[(kk + 0) * XS + r] = v.x;
            Xs[(kk + 1) * XS + r] = v.y;
            Xs[(kk + 2) * XS + r] = v.z;
            Xs[(kk + 3) * XS + r] = v.w;
        }
        {
            const float4* wsrc = (const float4*)(W + (size_t)kc * HID);
            #pragma unroll
            for (int it = 0; it < 4; ++it) {
                int id = t + 256 * it;          // k = id>>4 (local), col-group = id&15 == tx
                int kl = id >> 4;
                float4 raw = wsrc[id];
                float a = As[kc + kl], c = Cs[kc + kl];
                float4 sc;
                sc.x = a * raw.x; sc.y = a * raw.y; sc.z = a * raw.z; sc.w = a * raw.w;
                ((float4*)Wsm)[id] = sc;
                bp.x = fmaf(c, raw.x, bp.x);
                bp.y = fmaf(c, raw.y, bp.y);
                bp.z = fmaf(c, raw.z, bp.z);
                bp.w = fmaf(c, raw.w, bp.w);
            }
        }
        __syncthreads();
        #pragma unroll 8
        for (int k = 0; k < KC; ++k) {
            float4 xv = *(const float4*)&Xs[k * XS + 4 * ty];
            float4 wv = *(const float4*)&Wsm[k * HID + 4 * tx];
            acc[0][0] = fmaf(xv.x, wv.x, acc[0][0]);
            acc[0][1] = fmaf(xv.x, wv.y, acc[0][1]);
            acc[0][2] = fmaf(xv.x, wv.z, acc[0][2]);
            acc[0][3] = fmaf(xv.x, wv.w, acc[0][3]);
            acc[1][0] = fmaf(xv.y, wv.x, acc[1][0]);
            acc[1][1] = fmaf(xv.y, wv.y, acc[1][1]);
            acc[1][2] = fmaf(xv.y, wv.z, acc[1][2]);
            acc[1][3] = fmaf(xv.y, wv.w, acc[1][3]);
            acc[2][0] = fmaf(xv.z, wv.x, acc[2][0]);
            acc[2][1] = fmaf(xv.z, wv.y, acc[2][1]);
            acc[2][2] = fmaf(xv.z, wv.z, acc[2][2]);
            acc[2][3] = fmaf(xv.z, wv.w, acc[2][3]);
            acc[3][0] = fmaf(xv.w, wv.x, acc[3][0]);
            acc[3][1] = fmaf(xv.w, wv.y, acc[3][1]);
            acc[3][2] = fmaf(xv.w, wv.z, acc[3][2]);
            acc[3][3] = fmaf(xv.w, wv.w, acc[3][3]);
        }
        __syncthreads();
    }

    // finalize folded bias: reduce 16 row-groups per column (Xs scratch @2048, bfinal @3072)
    {
        float* redb = Xs + 2048;
        *(float4*)&redb[ty * 64 + 4 * tx] = bp;
        __syncthreads();
        if (t < 64) {
            float s = 0.f;
            #pragma unroll
            for (int k = 0; k < 16; ++k) s += redb[k * 64 + t];
            Xs[3072 + t] = s + (HASB ? bias0[t] : 0.f);
        }
        __syncthreads();
    }
    float4 bv = *(const float4*)&Xs[3072 + 4 * tx];

    float4 cs = make_float4(0.f, 0.f, 0.f, 0.f);
    float4 cq = make_float4(0.f, 0.f, 0.f, 0.f);
    #pragma unroll
    for (int i = 0; i < 4; ++i) {
        int row = row0 + 4 * ty + i;
        bool valid = row < n;
        float vx = acc[i][0] + bv.x, vy = acc[i][1] + bv.y;
        float vz = acc[i][2] + bv.z, vw = acc[i][3] + bv.w;
        if constexpr (DIS) {
            if (valid) {
                float d = dis[row];
                uint2 pk;
                pk.x = bf16pk(vx * d, vy * d);
                pk.y = bf16pk(vz * d, vw * d);
                *(uint2*)((ushort*)out + (size_t)row * HID + 4 * tx) = pk;
            }
        } else {
            float4 v;
            v.x = RELU ? fmaxf(vx, 0.f) : vx;
            v.y = RELU ? fmaxf(vy, 0.f) : vy;
            v.z = RELU ? fmaxf(vz, 0.f) : vz;
            v.w = RELU ? fmaxf(vw, 0.f) : vw;
            if (valid) {
                *(float4*)((float*)out + (size_t)row * HID + 4 * tx) = v;
                if constexpr (STATS) {
                    cs.x += v.x; cs.y += v.y; cs.z += v.z; cs.w += v.w;
                    cq.x = fmaf(v.x, v.x, cq.x); cq.y = fmaf(v.y, v.y, cq.y);
                    cq.z = fmaf(v.z, v.z, cq.z); cq.w = fmaf(v.w, v.w, cq.w);
                }
            }
        }
    }
    if constexpr (STATS) {
        __syncthreads();
        float* reds = Xs;
        float* redq = Xs + 1024;
        *(float4*)&reds[ty * 64 + 4 * tx] = cs;
        *(float4*)&redq[ty * 64 + 4 * tx] = cq;
        __syncthreads();
        if (t < 64) {
            float s = 0.f, q = 0.f;
            #pragma unroll
            for (int k = 0; k < 16; ++k) { s += reds[k * 64 + t]; q += redq[k * 64 + t]; }
            spartial[(size_t)blockIdx.x * 128 + t] = s;
            spartial[(size_t)blockIdx.x * 128 + 64 + t] = q;
        }
    }
}

// ============ aggregation (+ fused BN-stats partials for next layer) ============

template <bool STATS>
__global__ __launch_bounds__(256) void k_agg(const ushort* __restrict__ s, const int* __restrict__ rowptr,
                                             const int* __restrict__ eidx, const float* __restrict__ dis,
                                             const float* __restrict__ bias, float* __restrict__ out, int n,
                                             float* __restrict__ spartial) {
    int t = threadIdx.x;
    int nl = t >> 5;
    int li = t & 31;
    int i = blockIdx.x * 8 + nl;
    int f = li * 2;
    float2 r = make_float2(0.f, 0.f);
    bool valid = i < n;
    if (valid) {
        const uint* sp = (const uint*)s;
        uint v = sp[(size_t)i * 32 + li];
        float ax = bfl(v), ay = bfh(v);
        int q = rowptr[i], qe = rowptr[i + 1];
        for (; q + 8 <= qe; q += 8) {
            int j0 = eidx[q], j1 = eidx[q + 1], j2 = eidx[q + 2], j3 = eidx[q + 3];
            int j4 = eidx[q + 4], j5 = eidx[q + 5], j6 = eidx[q + 6], j7 = eidx[q + 7];
            uint v0 = sp[(size_t)j0 * 32 + li];
            uint v1 = sp[(size_t)j1 * 32 + li];
            uint v2 = sp[(size_t)j2 * 32 + li];
            uint v3 = sp[(size_t)j3 * 32 + li];
            uint v4 = sp[(size_t)j4 * 32 + li];
            uint v5 = sp[(size_t)j5 * 32 + li];
            uint v6 = sp[(size_t)j6 * 32 + li];
            uint v7 = sp[(size_t)j7 * 32 + li];
            ax += ((bfl(v0) + bfl(v1)) + (bfl(v2) + bfl(v3))) + ((bfl(v4) + bfl(v5)) + (bfl(v6) + bfl(v7)));
            ay += ((bfh(v0) + bfh(v1)) + (bfh(v2) + bfh(v3))) + ((bfh(v4) + bfh(v5)) + (bfh(v6) + bfh(v7)));
        }
        for (; q + 4 <= qe; q += 4) {
            int j0 = eidx[q], j1 = eidx[q + 1], j2 = eidx[q + 2], j3 = eidx[q + 3];
            uint v0 = sp[(size_t)j0 * 32 + li];
            uint v1 = sp[(size_t)j1 * 32 + li];
            uint v2 = sp[(size_t)j2 * 32 + li];
            uint v3 = sp[(size_t)j3 * 32 + li];
            ax += (bfl(v0) + bfl(v1)) + (bfl(v2) + bfl(v3));
            ay += (bfh(v0) + bfh(v1)) + (bfh(v2) + bfh(v3));
        }
        for (; q < qe; ++q) {
            uint vv = sp[(size_t)eidx[q] * 32 + li];
            ax += bfl(vv); ay += bfh(vv);
        }
        float dd = dis[i];
        float2 bb = *(const float2*)(bias + f);
        r.x = fmaxf(fmaf(dd, ax, bb.x), 0.f);
        r.y = fmaxf(fmaf(dd, ay, bb.y), 0.f);
        *(float2*)(out + (size_t)i * HID + f) = r;
    }
    if constexpr (STATS) {
        __shared__ float sh[8 * 64 * 2];
        sh[nl * 64 + f] = r.x;
        sh[nl * 64 + f + 1] = r.y;
        sh[512 + nl * 64 + f] = r.x * r.x;
        sh[512 + nl * 64 + f + 1] = r.y * r.y;
        __syncthreads();
        if (t < 64) {
            float ss = 0.f, qq = 0.f;
            #pragma unroll
            for (int k = 0; k < 8; ++k) { ss += sh[k * 64 + t]; qq += sh[512 + k * 64 + t]; }
            spartial[(size_t)blockIdx.x * 128 + t] = ss;
            spartial[(size_t)blockIdx.x * 128 + 64 + t] = qq;
        }
    }
}

// ============ global_add_pool ============

__global__ __launch_bounds__(256) void k_pool(const float* __restrict__ h, const int* __restrict__ batch,
                                              int n, float* __restrict__ out) {
    int g = blockIdx.x;
    int lo = 0, hi = n;
    while (lo < hi) { int mid = (lo + hi) >> 1; if (batch[mid] < g) lo = mid + 1; else hi = mid; }
    int start = lo;
    hi = n;
    while (lo < hi) { int mid = (lo + hi) >> 1; if (batch[mid] < g + 1) lo = mid + 1; else hi = mid; }
    int end = lo;
    int lane = threadIdx.x & 63;
    int rs = threadIdx.x >> 6;
    float acc = 0.f;
    for (int r = start + rs; r < end; r += 4) acc += h[(size_t)r * HID + lane];
    __shared__ float sh[256];
    sh[threadIdx.x] = acc;
    __syncthreads();
    if (threadIdx.x < 64) {
        acc = sh[threadIdx.x] + sh[64 + threadIdx.x] + sh[128 + threadIdx.x] + sh[192 + threadIdx.x];
        out[(size_t)g * HID + threadIdx.x] = acc;
    }
}

// ============ driver ============

extern "C" void kernel_launch(void* const* d_in, const int* in_sizes, int n_in,
                              void* d_out, int out_size, void* d_ws, size_t ws_size,
                              hipStream_t stream) {
    const float* x     = (const float*)d_in[0];
    const int*   ei    = (const int*)d_in[1];
    const int*   batch = (const int*)d_in[2];
    const float* bnfg  = (const float*)d_in[3];
    const float* bnfb  = (const float*)d_in[4];
    const float* Wfeat = (const float*)d_in[5];
    const float* bfeat = (const float*)d_in[6];
    const float* bng   = (const float*)d_in[7];
    const float* bnb   = (const float*)d_in[8];
    const float* Ws    = (const float*)d_in[9];
    const float* bs    = (const float*)d_in[10];
    float* out = (float*)d_out;

    const int N   = in_sizes[2];
    const int E   = in_sizes[1] / 2;
    const int L   = in_sizes[9] / (HID * HID);
    const int G   = out_size / HID;
    const int NB  = (N + 255) >> 8;
    const int SB  = 512;                    // stats<128> stage-1 blocks
    const int gG  = (N + 63) / 64;          // gemm blocks
    const int gA  = (N + 7) / 8;            // agg blocks
    const float n_inv = 1.f / (float)N;

    char* w = (char*)d_ws;
    auto alloc = [&](size_t bytes) { char* p = w; w += (bytes + 255) & ~(size_t)255; return p; };
    int*   bcnt_d = (int*)alloc(256 * 4);
    int*   bcnt_s = (int*)alloc(256 * 4);
    size_t zero_bytes = (size_t)(w - (char*)d_ws);
    float* stats    = (float*)alloc(1024 * 4);
    size_t spmax    = (size_t)(SB > gA ? SB : gA) * 256 * 4;
    float* spartial = (float*)alloc(spmax);
    int*   bbase_d  = (int*)alloc(257 * 4);
    int*   cursor_d = (int*)alloc(256 * 4);
    int*   bbase_s  = (int*)alloc(257 * 4);
    int*   cursor_s = (int*)alloc(256 * 4);
    int*   rowptr   = (int*)alloc(((size_t)N + 1) * 4);
    int*   eidx     = (int*)alloc((size_t)E * 4);
    float* dis      = (float*)alloc((size_t)N * 4);
    float* bufA     = (float*)alloc((size_t)N * HID * 4);
    ushort* bufB    = (ushort*)alloc((size_t)N * HID * 2);
    uint* bedge = (uint*)bufA;     // E*4 <= N*HID*4 ; consumed before bufA first written
    int*  bsrc  = (int*)bufB;      // E*4 <= N*HID*2 ; consumed before bufB first written

    hipMemsetAsync(d_ws, 0, zero_bytes, stream);

    // graph build
    k_bucket_hist<<<256, 256, 0, stream>>>(ei, E, NB, bcnt_d, bcnt_s);
    k_bucket_scan<<<1, 256, 0, stream>>>(bcnt_d, bcnt_s, NB, N, E,
                                         bbase_d, cursor_d, bbase_s, cursor_s, rowptr);
    k_scatter<<<256, 256, 0, stream>>>(ei, E, NB, cursor_d, cursor_s, bedge, bsrc);
    k_build_csr_outdeg<<<2 * NB, 256, 0, stream>>>(bedge, bbase_d, bsrc, bbase_s, N, NB,
                                                   rowptr, eidx, dis);

    // feature layer: stats(x) -> gemm<128> (fold fused, stats-of-output fused)
    k_stats<128><<<SB, 256, 0, stream>>>(x, N, spartial);
    k_stats_final<128><<<256, 256, 0, stream>>>(spartial, SB, stats);
    k_gemm<128, true, false, true, true><<<gG, 256, 0, stream>>>(
        x, Wfeat, stats, bnfg, bnfb, bfeat, nullptr, n_inv, (void*)bufA, N, spartial);
    int spblocks = gG;

    // GCN layers
    for (int l = 0; l < L; ++l) {
        k_stats_final<64><<<128, 256, 0, stream>>>(spartial, spblocks, stats);
        k_gemm<64, false, true, false, false><<<gG, 256, 0, stream>>>(
            bufA, Ws + (size_t)l * HID * HID, stats, bng + (size_t)l * HID, bnb + (size_t)l * HID,
            nullptr, dis, n_inv, (void*)bufB, N, nullptr);
        if (l < L - 1) {
            k_agg<true><<<gA, 256, 0, stream>>>(bufB, rowptr, eidx, dis, bs + (size_t)l * HID, bufA, N, spartial);
            spblocks = gA;
        } else {
            k_agg<false><<<gA, 256, 0, stream>>>(bufB, rowptr, eidx, dis, bs + (size_t)l * HID, bufA, N, nullptr);
        }
    }

    k_pool<<<G, 256, 0, stream>>>(bufA, batch, N, out);
}

// Round 12
// 299.341 us; speedup vs baseline: 6.6916x; 1.0300x over previous
//
#include <hip/hip_runtime.h>
#include <math.h>

#define HID 64
#define BN_EPS 1e-5f
#define NBMAX 256

typedef unsigned int uint;
typedef unsigned short ushort;

// ============ radix-bucketed CSR build ============
// edges packed to 32-bit ((dst&255)<<16 | src) — requires N < 65536 (N=50000 here).

__global__ __launch_bounds__(256) void k_bucket_hist(const int* __restrict__ ei, int E, int NB,
                                                     int* __restrict__ bcnt_d, int* __restrict__ bcnt_s) {
    __shared__ int hd[NBMAX], hs[NBMAX];
    int t = threadIdx.x;
    if (t < NB) { hd[t] = 0; hs[t] = 0; }
    __syncthreads();
    for (int e = blockIdx.x * 256 + t; e < E; e += gridDim.x * 256) {
        int src = ei[e], dst = ei[E + e];
        atomicAdd(&hs[src >> 8], 1);
        atomicAdd(&hd[dst >> 8], 1);
    }
    __syncthreads();
    if (t < NB) {
        if (hd[t]) atomicAdd(&bcnt_d[t], hd[t]);
        if (hs[t]) atomicAdd(&bcnt_s[t], hs[t]);
    }
}

__global__ __launch_bounds__(256) void k_bucket_scan(const int* __restrict__ bcnt_d, const int* __restrict__ bcnt_s,
                                                     int NB, int N, int E,
                                                     int* __restrict__ bbase_d, int* __restrict__ cursor_d,
                                                     int* __restrict__ bbase_s, int* __restrict__ cursor_s,
                                                     int* __restrict__ rowptr) {
    __shared__ int sh[256];
    int t = threadIdx.x;
    int v = (t < NB) ? bcnt_d[t] : 0;
    sh[t] = v; __syncthreads();
    for (int s = 1; s < 256; s <<= 1) { int u = (t >= s) ? sh[t - s] : 0; __syncthreads(); sh[t] += u; __syncthreads(); }
    int excl = sh[t] - v;
    if (t <= NB) bbase_d[t] = excl;
    if (t < NB) cursor_d[t] = excl;
    if (t == 0) rowptr[N] = E;
    __syncthreads();
    v = (t < NB) ? bcnt_s[t] : 0;
    sh[t] = v; __syncthreads();
    for (int s = 1; s < 256; s <<= 1) { int u = (t >= s) ? sh[t - s] : 0; __syncthreads(); sh[t] += u; __syncthreads(); }
    excl = sh[t] - v;
    if (t <= NB) bbase_s[t] = excl;
    if (t < NB) cursor_s[t] = excl;
}

// fused: blocks [0,SCB) scatter edges into buckets; blocks [SCB,SCB+SB) do BN-stats
// stage-1 over x (independent work, overlapped).
__global__ __launch_bounds__(256) void k_scatter_stats(const int* __restrict__ ei, int E, int NB, int SCB,
                                                       int* __restrict__ cursor_d, int* __restrict__ cursor_s,
                                                       uint* __restrict__ bedge, int* __restrict__ bsrc,
                                                       const float* __restrict__ X, int n,
                                                       float* __restrict__ spartial) {
    __shared__ __align__(16) char smemraw[8192];
    int t = threadIdx.x;
    if ((int)blockIdx.x < SCB) {
        int* hd = (int*)smemraw;            // 256
        int* hs = hd + 256;                 // 256
        int* curd = hs + 256;               // 256
        int* curs = curd + 256;             // 256 -> 4KB total
        int chunk = (E + SCB - 1) / SCB;
        int e0 = blockIdx.x * chunk;
        int e1 = min(e0 + chunk, E);
        if (t < NB) { hd[t] = 0; hs[t] = 0; }
        __syncthreads();
        for (int e = e0 + t; e < e1; e += 256) {
            int src = ei[e], dst = ei[E + e];
            atomicAdd(&hd[dst >> 8], 1);
            atomicAdd(&hs[src >> 8], 1);
        }
        __syncthreads();
        if (t < NB) {
            curd[t] = hd[t] ? atomicAdd(&cursor_d[t], hd[t]) : 0;
            curs[t] = hs[t] ? atomicAdd(&cursor_s[t], hs[t]) : 0;
        }
        __syncthreads();
        for (int e = e0 + t; e < e1; e += 256) {
            int src = ei[e], dst = ei[E + e];
            int pd = atomicAdd(&curd[dst >> 8], 1);
            bedge[pd] = ((uint)(dst & 255) << 16) | (uint)src;   // N < 65536
            int ps = atomicAdd(&curs[src >> 8], 1);
            bsrc[ps] = src;
        }
    } else {
        // BN stats stage-1 over x [n,128]
        int b = blockIdx.x - SCB;
        int SB = gridDim.x - SCB;
        float4* shs = (float4*)smemraw;     // needs 8KB -> use two halves of 4KB? no:
        // 256 float4 = 4KB for sums; reuse second half for sq
        float4* shq = shs + 256;            // 4KB more -> 8KB total, fits smemraw
        int c4 = t & 31, rsub = t >> 5;
        float4 s = make_float4(0.f, 0.f, 0.f, 0.f);
        float4 q = make_float4(0.f, 0.f, 0.f, 0.f);
        for (int r = b * 8 + rsub; r < n; r += SB * 8) {
            float4 v = ((const float4*)X)[(size_t)r * 32 + c4];
            s.x += v.x; s.y += v.y; s.z += v.z; s.w += v.w;
            q.x = fmaf(v.x, v.x, q.x); q.y = fmaf(v.y, v.y, q.y);
            q.z = fmaf(v.z, v.z, q.z); q.w = fmaf(v.w, v.w, q.w);
        }
        shs[t] = s; shq[t] = q;
        __syncthreads();
        if (rsub == 0) {
            #pragma unroll
            for (int k = 1; k < 8; k++) {
                float4 a = shs[t + k * 32], bq = shq[t + k * 32];
                s.x += a.x; s.y += a.y; s.z += a.z; s.w += a.w;
                q.x += bq.x; q.y += bq.y; q.z += bq.z; q.w += bq.w;
            }
            float* p = spartial + (size_t)b * 256;
            ((float4*)p)[c4] = s;
            ((float4*)(p + 128))[c4] = q;
        }
    }
}

// fused: blocks [0,NB) dst-CSR; [NB,2NB) outdeg->dis; [2NB,2NB+256) stats-final<128>
__global__ __launch_bounds__(256) void k_build_csr_outdeg_statsf(
        const uint* __restrict__ bedge, const int* __restrict__ bbase_d,
        const int* __restrict__ bsrc, const int* __restrict__ bbase_s,
        int N, int NB,
        int* __restrict__ rowptr, int* __restrict__ eidx, float* __restrict__ dis,
        const float* __restrict__ spartial, int snblocks, float* __restrict__ stats) {
    __shared__ int h[256], off[256], cur[256];
    int t = threadIdx.x, b = blockIdx.x;
    if (b < NB) {
        int base = bbase_d[b], end = bbase_d[b + 1];
        h[t] = 0; __syncthreads();
        for (int p = base + t; p < end; p += 256)
            atomicAdd(&h[(int)(bedge[p] >> 16) & 255], 1);
        __syncthreads();
        off[t] = h[t]; __syncthreads();
        for (int s = 1; s < 256; s <<= 1) { int u = (t >= s) ? off[t - s] : 0; __syncthreads(); off[t] += u; __syncthreads(); }
        int excl = off[t] - h[t];
        int node = (b << 8) + t;
        if (node <= N) rowptr[node] = base + excl;
        cur[t] = excl; __syncthreads();
        for (int p = base + t; p < end; p += 256) {
            uint be = bedge[p];
            int bin = (int)(be >> 16) & 255;
            int pos = atomicAdd(&cur[bin], 1);
            eidx[base + pos] = (int)(be & 0xffffu);
        }
    } else if (b < 2 * NB) {
        int b2 = b - NB;
        int base = bbase_s[b2], end = bbase_s[b2 + 1];
        h[t] = 0; __syncthreads();
        for (int p = base + t; p < end; p += 256) atomicAdd(&h[bsrc[p] & 255], 1);
        __syncthreads();
        int node = (b2 << 8) + t;
        if (node < N) dis[node] = rsqrtf((float)(h[t] + 1));
    } else {
        // stats-final<128>: column j = b - 2NB of spartial (stride 256)
        int j = b - 2 * NB;
        float* sh = (float*)h;    // reuse (only need 256 floats; h is 256 ints)
        float acc = 0.f;
        for (int bb = t; bb < snblocks; bb += 256) acc += spartial[(size_t)bb * 256 + j];
        sh[t] = acc;
        __syncthreads();
        #pragma unroll
        for (int o = 128; o > 0; o >>= 1) {
            if (t < o) sh[t] += sh[t + o];
            __syncthreads();
        }
        if (t == 0) stats[j] = sh[0];
    }
}

// stats-final for 64-feature layers: grid = 128 blocks
template <int F>
__global__ __launch_bounds__(256) void k_stats_final(const float* __restrict__ partial, int nblocks,
                                                     float* __restrict__ stats) {
    int j = blockIdx.x;
    int t = threadIdx.x;
    float acc = 0.f;
    for (int b = t; b < nblocks; b += 256) acc += partial[(size_t)b * (2 * F) + j];
    __shared__ float sh[256];
    sh[t] = acc;
    __syncthreads();
    #pragma unroll
    for (int off = 128; off > 0; off >>= 1) {
        if (t < off) sh[t] += sh[t + off];
        __syncthreads();
    }
    if (t == 0) stats[j] = sh[0];
}

// ============ GEMM with fused BN-fold prologue + optional stats epilogue ============

__device__ inline uint bf16pk(float a, float b) {
    uint ua = __builtin_bit_cast(uint, a);
    ua += 0x7fff + ((ua >> 16) & 1);
    uint ub = __builtin_bit_cast(uint, b);
    ub += 0x7fff + ((ub >> 16) & 1);
    return (ua >> 16) | (ub & 0xffff0000u);
}
__device__ inline float bfl(uint v) { return __builtin_bit_cast(float, v << 16); }
__device__ inline float bfh(uint v) { return __builtin_bit_cast(float, v & 0xffff0000u); }

template <int K, bool RELU, bool DIS, bool STATS, bool HASB>
__global__ __launch_bounds__(256) void k_gemm(const float* __restrict__ X, const float* __restrict__ W,
                                              const float* __restrict__ stats,
                                              const float* __restrict__ gamma, const float* __restrict__ beta,
                                              const float* __restrict__ bias0, const float* __restrict__ dis,
                                              float n_inv, void* __restrict__ out, int n,
                                              float* __restrict__ spartial) {
    constexpr int KC = 64;
    constexpr int XS = 68;
    __shared__ float Xs[KC * XS];
    __shared__ float Wsm[KC * HID];
    __shared__ float As[128], Cs[128];

    int t = threadIdx.x;
    int tx = t & 15, ty = t >> 4;
    int row0 = blockIdx.x * 64;

    if (t < K) {
        float mu = stats[t] * n_inv;
        float var = stats[K + t] * n_inv - mu * mu;
        float a = gamma[t] * rsqrtf(var + BN_EPS);
        As[t] = a;
        Cs[t] = beta[t] - mu * a;
    }
    __syncthreads();

    float acc[4][4];
    #pragma unroll
    for (int i = 0; i < 4; i++)
        #pragma unroll
        for (int j = 0; j < 4; j++) acc[i][j] = 0.f;
    float4 bp = make_float4(0.f, 0.f, 0.f, 0.f);

    for (int kc = 0; kc < K; kc += KC) {
        #pragma unroll
        for (int it = 0; it < 4; ++it) {
            int id = t + 256 * it;
            int r = id >> 4, c4 = id & 15;
            float4 v = make_float4(0.f, 0.f, 0.f, 0.f);
            if (row0 + r < n) v = *(const float4*)(X + (size_t)(row0 + r) * K + kc + 4 * c4);
            int kk = 4 * c4;
            Xs[(kk + 0) * XS + r] = v.x;
            Xs[(kk + 1) * XS + r] = v.y;
            Xs[(kk + 2) * XS + r] = v.z;
            Xs[(kk + 3) * XS + r] = v.w;
        }
        {
            const float4* wsrc = (const float4*)(W + (size_t)kc * HID);
            #pragma unroll
            for (int it = 0; it < 4; ++it) {
                int id = t + 256 * it;
                int kl = id >> 4;
                float4 raw = wsrc[id];
                float a = As[kc + kl], c = Cs[kc + kl];
                float4 sc;
                sc.x = a * raw.x; sc.y = a * raw.y; sc.z = a * raw.z; sc.w = a * raw.w;
                ((float4*)Wsm)[id] = sc;
                bp.x = fmaf(c, raw.x, bp.x);
                bp.y = fmaf(c, raw.y, bp.y);
                bp.z = fmaf(c, raw.z, bp.z);
                bp.w = fmaf(c, raw.w, bp.w);
            }
        }
        __syncthreads();
        #pragma unroll 8
        for (int k = 0; k < KC; ++k) {
            float4 xv = *(const float4*)&Xs[k * XS + 4 * ty];
            float4 wv = *(const float4*)&Wsm[k * HID + 4 * tx];
            acc[0][0] = fmaf(xv.x, wv.x, acc[0][0]);
            acc[0][1] = fmaf(xv.x, wv.y, acc[0][1]);
            acc[0][2] = fmaf(xv.x, wv.z, acc[0][2]);
            acc[0][3] = fmaf(xv.x, wv.w, acc[0][3]);
            acc[1][0] = fmaf(xv.y, wv.x, acc[1][0]);
            acc[1][1] = fmaf(xv.y, wv.y, acc[1][1]);
            acc[1][2] = fmaf(xv.y, wv.z, acc[1][2]);
            acc[1][3] = fmaf(xv.y, wv.w, acc[1][3]);
            acc[2][0] = fmaf(xv.z, wv.x, acc[2][0]);
            acc[2][1] = fmaf(xv.z, wv.y, acc[2][1]);
            acc[2][2] = fmaf(xv.z, wv.z, acc[2][2]);
            acc[2][3] = fmaf(xv.z, wv.w, acc[2][3]);
            acc[3][0] = fmaf(xv.w, wv.x, acc[3][0]);
            acc[3][1] = fmaf(xv.w, wv.y, acc[3][1]);
            acc[3][2] = fmaf(xv.w, wv.z, acc[3][2]);
            acc[3][3] = fmaf(xv.w, wv.w, acc[3][3]);
        }
        __syncthreads();
    }

    {
        float* redb = Xs + 2048;
        *(float4*)&redb[ty * 64 + 4 * tx] = bp;
        __syncthreads();
        if (t < 64) {
            float s = 0.f;
            #pragma unroll
            for (int k = 0; k < 16; ++k) s += redb[k * 64 + t];
            Xs[3072 + t] = s + (HASB ? bias0[t] : 0.f);
        }
        __syncthreads();
    }
    float4 bv = *(const float4*)&Xs[3072 + 4 * tx];

    float4 cs = make_float4(0.f, 0.f, 0.f, 0.f);
    float4 cq = make_float4(0.f, 0.f, 0.f, 0.f);
    #pragma unroll
    for (int i = 0; i < 4; ++i) {
        int row = row0 + 4 * ty + i;
        bool valid = row < n;
        float vx = acc[i][0] + bv.x, vy = acc[i][1] + bv.y;
        float vz = acc[i][2] + bv.z, vw = acc[i][3] + bv.w;
        if constexpr (DIS) {
            if (valid) {
                float d = dis[row];
                uint2 pk;
                pk.x = bf16pk(vx * d, vy * d);
                pk.y = bf16pk(vz * d, vw * d);
                *(uint2*)((ushort*)out + (size_t)row * HID + 4 * tx) = pk;
            }
        } else {
            float4 v;
            v.x = RELU ? fmaxf(vx, 0.f) : vx;
            v.y = RELU ? fmaxf(vy, 0.f) : vy;
            v.z = RELU ? fmaxf(vz, 0.f) : vz;
            v.w = RELU ? fmaxf(vw, 0.f) : vw;
            if (valid) {
                *(float4*)((float*)out + (size_t)row * HID + 4 * tx) = v;
                if constexpr (STATS) {
                    cs.x += v.x; cs.y += v.y; cs.z += v.z; cs.w += v.w;
                    cq.x = fmaf(v.x, v.x, cq.x); cq.y = fmaf(v.y, v.y, cq.y);
                    cq.z = fmaf(v.z, v.z, cq.z); cq.w = fmaf(v.w, v.w, cq.w);
                }
            }
        }
    }
    if constexpr (STATS) {
        __syncthreads();
        float* reds = Xs;
        float* redq = Xs + 1024;
        *(float4*)&reds[ty * 64 + 4 * tx] = cs;
        *(float4*)&redq[ty * 64 + 4 * tx] = cq;
        __syncthreads();
        if (t < 64) {
            float s = 0.f, q = 0.f;
            #pragma unroll
            for (int k = 0; k < 16; ++k) { s += reds[k * 64 + t]; q += redq[k * 64 + t]; }
            spartial[(size_t)blockIdx.x * 128 + t] = s;
            spartial[(size_t)blockIdx.x * 128 + 64 + t] = q;
        }
    }
}

// ============ aggregation (+ fused BN-stats partials for next layer) ============

template <bool STATS>
__global__ __launch_bounds__(256) void k_agg(const ushort* __restrict__ s, const int* __restrict__ rowptr,
                                             const int* __restrict__ eidx, const float* __restrict__ dis,
                                             const float* __restrict__ bias, float* __restrict__ out, int n,
                                             float* __restrict__ spartial) {
    int t = threadIdx.x;
    int nl = t >> 5;
    int li = t & 31;
    int i = blockIdx.x * 8 + nl;
    int f = li * 2;
    float2 r = make_float2(0.f, 0.f);
    bool valid = i < n;
    if (valid) {
        const uint* sp = (const uint*)s;
        uint v = sp[(size_t)i * 32 + li];
        float ax = bfl(v), ay = bfh(v);
        int q = rowptr[i], qe = rowptr[i + 1];
        for (; q + 8 <= qe; q += 8) {
            int j0 = eidx[q], j1 = eidx[q + 1], j2 = eidx[q + 2], j3 = eidx[q + 3];
            int j4 = eidx[q + 4], j5 = eidx[q + 5], j6 = eidx[q + 6], j7 = eidx[q + 7];
            uint v0 = sp[(size_t)j0 * 32 + li];
            uint v1 = sp[(size_t)j1 * 32 + li];
            uint v2 = sp[(size_t)j2 * 32 + li];
            uint v3 = sp[(size_t)j3 * 32 + li];
            uint v4 = sp[(size_t)j4 * 32 + li];
            uint v5 = sp[(size_t)j5 * 32 + li];
            uint v6 = sp[(size_t)j6 * 32 + li];
            uint v7 = sp[(size_t)j7 * 32 + li];
            ax += ((bfl(v0) + bfl(v1)) + (bfl(v2) + bfl(v3))) + ((bfl(v4) + bfl(v5)) + (bfl(v6) + bfl(v7)));
            ay += ((bfh(v0) + bfh(v1)) + (bfh(v2) + bfh(v3))) + ((bfh(v4) + bfh(v5)) + (bfh(v6) + bfh(v7)));
        }
        for (; q + 4 <= qe; q += 4) {
            int j0 = eidx[q], j1 = eidx[q + 1], j2 = eidx[q + 2], j3 = eidx[q + 3];
            uint v0 = sp[(size_t)j0 * 32 + li];
            uint v1 = sp[(size_t)j1 * 32 + li];
            uint v2 = sp[(size_t)j2 * 32 + li];
            uint v3 = sp[(size_t)j3 * 32 + li];
            ax += (bfl(v0) + bfl(v1)) + (bfl(v2) + bfl(v3));
            ay += (bfh(v0) + bfh(v1)) + (bfh(v2) + bfh(v3));
        }
        for (; q < qe; ++q) {
            uint vv = sp[(size_t)eidx[q] * 32 + li];
            ax += bfl(vv); ay += bfh(vv);
        }
        float dd = dis[i];
        float2 bb = *(const float2*)(bias + f);
        r.x = fmaxf(fmaf(dd, ax, bb.x), 0.f);
        r.y = fmaxf(fmaf(dd, ay, bb.y), 0.f);
        *(float2*)(out + (size_t)i * HID + f) = r;
    }
    if constexpr (STATS) {
        __shared__ float sh[8 * 64 * 2];
        sh[nl * 64 + f] = r.x;
        sh[nl * 64 + f + 1] = r.y;
        sh[512 + nl * 64 + f] = r.x * r.x;
        sh[512 + nl * 64 + f + 1] = r.y * r.y;
        __syncthreads();
        if (t < 64) {
            float ss = 0.f, qq = 0.f;
            #pragma unroll
            for (int k = 0; k < 8; ++k) { ss += sh[k * 64 + t]; qq += sh[512 + k * 64 + t]; }
            spartial[(size_t)blockIdx.x * 128 + t] = ss;
            spartial[(size_t)blockIdx.x * 128 + 64 + t] = qq;
        }
    }
}

// ============ global_add_pool ============

__global__ __launch_bounds__(256) void k_pool(const float* __restrict__ h, const int* __restrict__ batch,
                                              int n, float* __restrict__ out) {
    int g = blockIdx.x;
    int lo = 0, hi = n;
    while (lo < hi) { int mid = (lo + hi) >> 1; if (batch[mid] < g) lo = mid + 1; else hi = mid; }
    int start = lo;
    hi = n;
    while (lo < hi) { int mid = (lo + hi) >> 1; if (batch[mid] < g + 1) lo = mid + 1; else hi = mid; }
    int end = lo;
    int lane = threadIdx.x & 63;
    int rs = threadIdx.x >> 6;
    float acc = 0.f;
    for (int r = start + rs; r < end; r += 4) acc += h[(size_t)r * HID + lane];
    __shared__ float sh[256];
    sh[threadIdx.x] = acc;
    __syncthreads();
    if (threadIdx.x < 64) {
        acc = sh[threadIdx.x] + sh[64 + threadIdx.x] + sh[128 + threadIdx.x] + sh[192 + threadIdx.x];
        out[(size_t)g * HID + threadIdx.x] = acc;
    }
}

// ============ driver ============

extern "C" void kernel_launch(void* const* d_in, const int* in_sizes, int n_in,
                              void* d_out, int out_size, void* d_ws, size_t ws_size,
                              hipStream_t stream) {
    const float* x     = (const float*)d_in[0];
    const int*   ei    = (const int*)d_in[1];
    const int*   batch = (const int*)d_in[2];
    const float* bnfg  = (const float*)d_in[3];
    const float* bnfb  = (const float*)d_in[4];
    const float* Wfeat = (const float*)d_in[5];
    const float* bfeat = (const float*)d_in[6];
    const float* bng   = (const float*)d_in[7];
    const float* bnb   = (const float*)d_in[8];
    const float* Ws    = (const float*)d_in[9];
    const float* bs    = (const float*)d_in[10];
    float* out = (float*)d_out;

    const int N   = in_sizes[2];
    const int E   = in_sizes[1] / 2;
    const int L   = in_sizes[9] / (HID * HID);
    const int G   = out_size / HID;
    const int NB  = (N + 255) >> 8;
    const int SCB = 256;                    // scatter blocks
    const int SB  = 512;                    // stats<128> stage-1 blocks
    const int gG  = (N + 63) / 64;          // gemm blocks
    const int gA  = (N + 7) / 8;            // agg blocks
    const float n_inv = 1.f / (float)N;

    char* w = (char*)d_ws;
    auto alloc = [&](size_t bytes) { char* p = w; w += (bytes + 255) & ~(size_t)255; return p; };
    int*   bcnt_d = (int*)alloc(256 * 4);
    int*   bcnt_s = (int*)alloc(256 * 4);
    size_t zero_bytes = (size_t)(w - (char*)d_ws);
    float* stats    = (float*)alloc(1024 * 4);
    size_t spmax    = (size_t)(SB > gA ? SB : gA) * 256 * 4;
    float* spartial = (float*)alloc(spmax);
    int*   bbase_d  = (int*)alloc(257 * 4);
    int*   cursor_d = (int*)alloc(256 * 4);
    int*   bbase_s  = (int*)alloc(257 * 4);
    int*   cursor_s = (int*)alloc(256 * 4);
    int*   rowptr   = (int*)alloc(((size_t)N + 1) * 4);
    int*   eidx     = (int*)alloc((size_t)E * 4);
    float* dis      = (float*)alloc((size_t)N * 4);
    float* bufA     = (float*)alloc((size_t)N * HID * 4);
    ushort* bufB    = (ushort*)alloc((size_t)N * HID * 2);
    uint* bedge = (uint*)bufA;     // E*4 <= N*HID*4 ; consumed before bufA first written
    int*  bsrc  = (int*)bufB;      // E*4 <= N*HID*2 ; consumed before bufB first written

    hipMemsetAsync(d_ws, 0, zero_bytes, stream);

    // graph build (+ overlapped stats over x)
    k_bucket_hist<<<512, 256, 0, stream>>>(ei, E, NB, bcnt_d, bcnt_s);
    k_bucket_scan<<<1, 256, 0, stream>>>(bcnt_d, bcnt_s, NB, N, E,
                                         bbase_d, cursor_d, bbase_s, cursor_s, rowptr);
    k_scatter_stats<<<SCB + SB, 256, 0, stream>>>(ei, E, NB, SCB, cursor_d, cursor_s,
                                                  bedge, bsrc, x, N, spartial);
    k_build_csr_outdeg_statsf<<<2 * NB + 256, 256, 0, stream>>>(
        bedge, bbase_d, bsrc, bbase_s, N, NB, rowptr, eidx, dis, spartial, SB, stats);

    // feature layer: gemm<128> (fold fused, stats-of-output fused)
    k_gemm<128, true, false, true, true><<<gG, 256, 0, stream>>>(
        x, Wfeat, stats, bnfg, bnfb, bfeat, nullptr, n_inv, (void*)bufA, N, spartial);
    int spblocks = gG;

    // GCN layers
    for (int l = 0; l < L; ++l) {
        k_stats_final<64><<<128, 256, 0, stream>>>(spartial, spblocks, stats);
        k_gemm<64, false, true, false, false><<<gG, 256, 0, stream>>>(
            bufA, Ws + (size_t)l * HID * HID, stats, bng + (size_t)l * HID, bnb + (size_t)l * HID,
            nullptr, dis, n_inv, (void*)bufB, N, nullptr);
        if (l < L - 1) {
            k_agg<true><<<gA, 256, 0, stream>>>(bufB, rowptr, eidx, dis, bs + (size_t)l * HID, bufA, N, spartial);
            spblocks = gA;
        } else {
            k_agg<false><<<gA, 256, 0, stream>>>(bufB, rowptr, eidx, dis, bs + (size_t)l * HID, bufA, N, nullptr);
        }
    }

    k_pool<<<G, 256, 0, stream>>>(bufA, batch, N, out);
}